// Round 2
// baseline (184.669 us; speedup 1.0000x reference)
//
#include <hip/hip_runtime.h>
#include <stdint.h>

#define N 2048
#define TILE 128
#define BK 32
#define NN ((size_t)N * (size_t)N)

typedef unsigned short u16;
typedef __bf16 bf16x8 __attribute__((ext_vector_type(8)));
typedef unsigned short ushortx8 __attribute__((ext_vector_type(8)));
typedef unsigned short ushortx4 __attribute__((ext_vector_type(4)));
typedef float floatx4 __attribute__((ext_vector_type(4)));

static __device__ __forceinline__ u16 f2bf(float f) {
  unsigned int u = __builtin_bit_cast(unsigned int, f);
  return (u16)((u + 0x7fffu + ((u >> 16) & 1u)) >> 16);  // RNE, finite inputs
}
static __device__ __forceinline__ float bf2f(u16 h) {
  unsigned int u = ((unsigned int)h) << 16;
  return __builtin_bit_cast(float, u);
}

// async global->LDS, 16B per lane; LDS dest = wave-uniform base + lane*16
static __device__ __forceinline__ void cp16(u16* lds, const u16* g) {
  __builtin_amdgcn_global_load_lds((const __attribute__((address_space(1))) void*)g,
                                   (__attribute__((address_space(3))) void*)lds,
                                   16, 0, 0);
}

// ---------------------------------------------------------------------------
// cast + transpose: Ab[r][c] = bf16(A[r][c]); Abt[c][r] = bf16(A[r][c])
// ---------------------------------------------------------------------------
__global__ void cast_tr(const float* __restrict__ A, u16* __restrict__ Ab,
                        u16* __restrict__ Abt) {
  __shared__ float tile[32][33];
  const int tx = threadIdx.x, ty = threadIdx.y;
  const int c = blockIdx.x * 32 + tx;
#pragma unroll
  for (int i = 0; i < 4; i++) {
    const int r = blockIdx.y * 32 + ty + i * 8;
    const float v = A[r * N + c];
    Ab[r * N + c] = f2bf(v);
    tile[ty + i * 8][tx] = v;
  }
  __syncthreads();
  const int r2 = blockIdx.y * 32 + tx;
#pragma unroll
  for (int i = 0; i < 4; i++) {
    const int c2 = blockIdx.x * 32 + ty + i * 8;
    Abt[c2 * N + r2] = f2bf(tile[tx][ty + i * 8]);
  }
}

// ---------------------------------------------------------------------------
// Split-K GEMM: P[z] += L[128 x ksl] * R[ksl x 128] (Rt in [n][k] layout).
// grid (16,16,NZ). Output: bf16 partials in wave-packed layout:
//   P[z*NN + blk*16384 + w*4096 + (mt*4+nt)*256 + lane*4 + r]
// so every epilogue store is a coalesced 512B/wave dwordx2.
// ---------------------------------------------------------------------------
__global__ __launch_bounds__(256, 2) void gemm_sk(const u16* __restrict__ L,
                                                  const u16* __restrict__ Rt,
                                                  u16* __restrict__ P,
                                                  int ksl) {
  __shared__ __align__(16) u16 As[TILE * BK];
  __shared__ __align__(16) u16 Bs[TILE * BK];

  const int t = threadIdx.x;
  const int row0 = blockIdx.y * TILE;
  const int col0 = blockIdx.x * TILE;
  const int kbeg = blockIdx.z * ksl;
  const int kend = kbeg + ksl;

  const int crow = t >> 2;
  const int coff = (t & 3) * 8;
  const u16* gA0 = L + (size_t)(row0 + crow) * N + coff;
  const u16* gA1 = gA0 + (size_t)64 * N;
  const u16* gB0 = Rt + (size_t)(col0 + crow) * N + coff;
  const u16* gB1 = gB0 + (size_t)64 * N;
  u16* lA0 = As + t * 8;
  u16* lA1 = As + 2048 + t * 8;
  u16* lB0 = Bs + t * 8;
  u16* lB1 = Bs + 2048 + t * 8;

  const int lane = t & 63;
  const int w = t >> 6;
  const int wr = (w >> 1) * 64;
  const int wc = (w & 1) * 64;
  const int lr = lane & 15;
  const int q = lane >> 4;

  floatx4 acc[4][4];
#pragma unroll
  for (int i = 0; i < 4; i++)
#pragma unroll
    for (int j = 0; j < 4; j++) acc[i][j] = (floatx4){0.f, 0.f, 0.f, 0.f};

  for (int k0 = kbeg; k0 < kend; k0 += BK) {
    cp16(lA0, gA0 + k0);
    cp16(lA1, gA1 + k0);
    cp16(lB0, gB0 + k0);
    cp16(lB1, gB1 + k0);
    __syncthreads();

    bf16x8 a[4], b[4];
#pragma unroll
    for (int mt = 0; mt < 4; mt++)
      a[mt] = __builtin_bit_cast(
          bf16x8, *(const ushortx8*)&As[(wr + mt * 16 + lr) * BK + q * 8]);
#pragma unroll
    for (int nt = 0; nt < 4; nt++)
      b[nt] = __builtin_bit_cast(
          bf16x8, *(const ushortx8*)&Bs[(wc + nt * 16 + lr) * BK + q * 8]);
#pragma unroll
    for (int mt = 0; mt < 4; mt++)
#pragma unroll
      for (int nt = 0; nt < 4; nt++)
        acc[mt][nt] = __builtin_amdgcn_mfma_f32_16x16x32_bf16(
            a[mt], b[nt], acc[mt][nt], 0, 0, 0);
    __syncthreads();
  }

  u16* Pp = P + (size_t)blockIdx.z * NN +
            (size_t)(blockIdx.y * gridDim.x + blockIdx.x) * (TILE * TILE) +
            (size_t)w * 4096 + (size_t)lane * 4;
#pragma unroll
  for (int mt = 0; mt < 4; mt++)
#pragma unroll
    for (int nt = 0; nt < 4; nt++) {
      ushortx4 v;
#pragma unroll
      for (int r = 0; r < 4; r++) v[r] = f2bf(acc[mt][nt][r]);
      *(ushortx4*)(Pp + (mt * 4 + nt) * 256) = v;
    }
}

// ---------------------------------------------------------------------------
// reduce1: Mb = bf16(sum_z P[z]) row-major; deg[row] += rowsum within tile.
// grid 256 (one per 128x128 tile), 256 threads mirroring gemm's lane map.
// ---------------------------------------------------------------------------
__global__ __launch_bounds__(256) void reduce1(const u16* __restrict__ P,
                                               u16* __restrict__ Mb,
                                               float* __restrict__ deg,
                                               int nz) {
  __shared__ float rs[TILE];
  const int t = threadIdx.x;
  const int blk = blockIdx.x;
  const int bx = blk & 15, by = blk >> 4;
  const int row0 = by * TILE, col0 = bx * TILE;
  const int lane = t & 63, w = t >> 6;
  const int wr = (w >> 1) * 64, wc = (w & 1) * 64;
  const int lr = lane & 15, q = lane >> 4;
  if (t < TILE) rs[t] = 0.f;
  __syncthreads();

  const u16* Pp = P + (size_t)blk * (TILE * TILE) + (size_t)w * 4096 +
                  (size_t)lane * 4;
  float trs[4][4];
#pragma unroll
  for (int i = 0; i < 4; i++)
#pragma unroll
    for (int j = 0; j < 4; j++) trs[i][j] = 0.f;

#pragma unroll
  for (int p = 0; p < 16; p++) {
    const int mt = p >> 2, nt = p & 3;
    float s[4] = {0.f, 0.f, 0.f, 0.f};
    for (int z = 0; z < nz; z++) {
      ushortx4 v = *(const ushortx4*)(Pp + (size_t)z * NN + p * 256);
#pragma unroll
      for (int r = 0; r < 4; r++) s[r] += bf2f(v[r]);
    }
    const int rr = row0 + wr + mt * 16 + q * 4;
    const int cc = col0 + wc + nt * 16 + lr;
#pragma unroll
    for (int r = 0; r < 4; r++) {
      Mb[(size_t)(rr + r) * N + cc] = f2bf(s[r]);
      trs[mt][r] += s[r];
    }
  }
#pragma unroll
  for (int mt = 0; mt < 4; mt++)
#pragma unroll
    for (int r = 0; r < 4; r++)
      atomicAdd(&rs[wr + mt * 16 + q * 4 + r], trs[mt][r]);
  __syncthreads();
  if (t < TILE) atomicAdd(&deg[row0 + t], rs[t]);
}

// ---------------------------------------------------------------------------
// reduce2: out = (8*sum_z Q[z] + 2*A) / (4*deg+1), row-scaled.
// ---------------------------------------------------------------------------
__global__ __launch_bounds__(256) void reduce2(const u16* __restrict__ Q,
                                               const float* __restrict__ A,
                                               const float* __restrict__ deg,
                                               float* __restrict__ out,
                                               int nz) {
  __shared__ float rdeg[TILE];
  const int t = threadIdx.x;
  const int blk = blockIdx.x;
  const int bx = blk & 15, by = blk >> 4;
  const int row0 = by * TILE, col0 = bx * TILE;
  const int lane = t & 63, w = t >> 6;
  const int wr = (w >> 1) * 64, wc = (w & 1) * 64;
  const int lr = lane & 15, q = lane >> 4;
  if (t < TILE) {
    float d = 4.f * deg[row0 + t] + 1.f;
    if (d <= 1e-10f) d = 1.f;
    rdeg[t] = 1.f / d;
  }
  __syncthreads();

  const u16* Qp = Q + (size_t)blk * (TILE * TILE) + (size_t)w * 4096 +
                  (size_t)lane * 4;
#pragma unroll
  for (int p = 0; p < 16; p++) {
    const int mt = p >> 2, nt = p & 3;
    float s[4] = {0.f, 0.f, 0.f, 0.f};
    for (int z = 0; z < nz; z++) {
      ushortx4 v = *(const ushortx4*)(Qp + (size_t)z * NN + p * 256);
#pragma unroll
      for (int r = 0; r < 4; r++) s[r] += bf2f(v[r]);
    }
    const int rr = row0 + wr + mt * 16 + q * 4;
    const int cc = col0 + wc + nt * 16 + lr;
#pragma unroll
    for (int r = 0; r < 4; r++)
      out[(size_t)(rr + r) * N + cc] =
          (8.f * s[r] + 2.f * A[(size_t)(rr + r) * N + cc]) *
          rdeg[wr + mt * 16 + q * 4 + r];
  }
}

extern "C" void kernel_launch(void* const* d_in, const int* in_sizes, int n_in,
                              void* d_out, int out_size, void* d_ws, size_t ws_size,
                              hipStream_t stream) {
  const float* A = (const float*)d_in[0];
  // GTConv weights (d_in[1..3]) are irrelevant: softmax over a singleton axis
  // is identically 1, so each conv output is exactly 2*A.
  float* out = (float*)d_out;
  char* ws = (char*)d_ws;
  u16* Ab = (u16*)ws;                          // 8 MB
  u16* Abt = (u16*)(ws + NN * 2);              // 8 MB
  u16* Mb = (u16*)(ws + NN * 4);               // 8 MB
  u16* P = (u16*)(ws + NN * 6);                // NZ * 8 MB partials (reused)

  const size_t need4 = NN * 6 + NN * 2 * 4 + (size_t)N * 4;
  const int nz = (ws_size >= need4) ? 4 : 1;
  float* deg = (float*)(ws + NN * 6 + NN * 2 * (size_t)nz);

  hipMemsetAsync(deg, 0, N * sizeof(float), stream);
  cast_tr<<<dim3(N / 32, N / 32), dim3(32, 8), 0, stream>>>(A, Ab, Abt);
  gemm_sk<<<dim3(16, 16, nz), 256, 0, stream>>>(Ab, Abt, P, N / nz);
  reduce1<<<256, 256, 0, stream>>>(P, Mb, deg, nz);
  gemm_sk<<<dim3(16, 16, nz), 256, 0, stream>>>(Mb, Abt, P, N / nz);
  reduce2<<<256, 256, 0, stream>>>(P, A, deg, out, nz);
}

// Round 3
// 164.230 us; speedup vs baseline: 1.1245x; 1.1245x over previous
//
#include <hip/hip_runtime.h>
#include <stdint.h>

#define N 2048
#define TILE 128
#define BK 32
#define KI (N / BK)      // 64 K-iterations
#define STAGES 4         // LDS ring depth; prefetch distance 3
#define NN ((size_t)N * (size_t)N)

typedef unsigned short u16;
typedef __bf16 bf16x8 __attribute__((ext_vector_type(8)));
typedef unsigned short ushortx8 __attribute__((ext_vector_type(8)));
typedef float floatx4 __attribute__((ext_vector_type(4)));

static __device__ __forceinline__ u16 f2bf(float f) {
  unsigned int u = __builtin_bit_cast(unsigned int, f);
  return (u16)((u + 0x7fffu + ((u >> 16) & 1u)) >> 16);  // RNE, finite inputs
}
static __device__ __forceinline__ float bf2f(u16 h) {
  unsigned int u = ((unsigned int)h) << 16;
  return __builtin_bit_cast(float, u);
}

// async global->LDS, 16B per lane; LDS dest = wave-uniform base + lane*16
static __device__ __forceinline__ void cp16(u16* lds, const u16* g) {
  __builtin_amdgcn_global_load_lds((const __attribute__((address_space(1))) void*)g,
                                   (__attribute__((address_space(3))) void*)lds,
                                   16, 0, 0);
}

// ---------------------------------------------------------------------------
// cast + transpose: Ab[r][c] = bf16(A[r][c]); Abt[c][r] = bf16(A[r][c])
// ---------------------------------------------------------------------------
__global__ void cast_tr(const float* __restrict__ A, u16* __restrict__ Ab,
                        u16* __restrict__ Abt) {
  __shared__ float tile[32][33];
  const int tx = threadIdx.x, ty = threadIdx.y;
  const int c = blockIdx.x * 32 + tx;
#pragma unroll
  for (int i = 0; i < 4; i++) {
    const int r = blockIdx.y * 32 + ty + i * 8;
    const float v = A[r * N + c];
    Ab[r * N + c] = f2bf(v);
    tile[ty + i * 8][tx] = v;
  }
  __syncthreads();
  const int r2 = blockIdx.y * 32 + tx;
#pragma unroll
  for (int i = 0; i < 4; i++) {
    const int c2 = blockIdx.x * 32 + ty + i * 8;
    Abt[c2 * N + r2] = f2bf(tile[tx][ty + i * 8]);
  }
}

// ---------------------------------------------------------------------------
// Pipelined GEMM tile: C = L[128 x N] * R[N x 128] (Rt in [n][k] layout).
// 4-stage LDS ring, prefetch depth 3, ONE raw s_barrier per K-iter,
// fine-grained vmcnt so next-stage DMAs stay in flight across the barrier.
// Safety: stage (i+3)&3 == (i-1)&3 is overwritten only AFTER the barrier
// that all waves reach having finished compute(i-1); DMA completion for
// stage i is guaranteed per-wave by vmcnt(8) then published by the barrier.
// ---------------------------------------------------------------------------
__device__ __forceinline__ void gemm_tile(const u16* __restrict__ L,
                                          const u16* __restrict__ Rt,
                                          floatx4 acc[4][4]) {
  __shared__ __align__(16) u16 As[STAGES][TILE * BK];
  __shared__ __align__(16) u16 Bs[STAGES][TILE * BK];

  const int t = threadIdx.x;
  const int row0 = blockIdx.y * TILE;
  const int col0 = blockIdx.x * TILE;

  const int crow = t >> 2;          // 0..63
  const int coff = (t & 3) * 8;     // u16 offset within a 32-wide k-slice
  const u16* gA0 = L + (size_t)(row0 + crow) * N + coff;
  const u16* gA1 = gA0 + (size_t)64 * N;
  const u16* gB0 = Rt + (size_t)(col0 + crow) * N + coff;
  const u16* gB1 = gB0 + (size_t)64 * N;

  const int lane = t & 63;
  const int w = t >> 6;
  const int wr = (w >> 1) * 64;
  const int wc = (w & 1) * 64;
  const int lr = lane & 15;
  const int q = lane >> 4;

#pragma unroll
  for (int i = 0; i < 4; i++)
#pragma unroll
    for (int j = 0; j < 4; j++) acc[i][j] = (floatx4){0.f, 0.f, 0.f, 0.f};

  // prologue: stages 0..2 in flight (12 loads/wave outstanding)
#pragma unroll
  for (int s = 0; s < 3; s++) {
    const int k0 = s * BK;
    cp16(&As[s][t * 8], gA0 + k0);
    cp16(&As[s][2048 + t * 8], gA1 + k0);
    cp16(&Bs[s][t * 8], gB0 + k0);
    cp16(&Bs[s][2048 + t * 8], gB1 + k0);
  }

  for (int i = 0; i < KI; ++i) {
    // retire stage i's 4 loads (per wave), leave newer stages in flight
    if (i < KI - 2)
      asm volatile("s_waitcnt vmcnt(8)" ::: "memory");
    else if (i == KI - 2)
      asm volatile("s_waitcnt vmcnt(4)" ::: "memory");
    else
      asm volatile("s_waitcnt vmcnt(0)" ::: "memory");
    asm volatile("s_barrier" ::: "memory");

    // prefetch stage i+3 (overwrites ring slot (i-1)&3 — safe post-barrier)
    if (i + 3 < KI) {
      const int s = (i + 3) & (STAGES - 1);
      const int k0 = (i + 3) * BK;
      cp16(&As[s][t * 8], gA0 + k0);
      cp16(&As[s][2048 + t * 8], gA1 + k0);
      cp16(&Bs[s][t * 8], gB0 + k0);
      cp16(&Bs[s][2048 + t * 8], gB1 + k0);
    }

    const int cur = i & (STAGES - 1);
    bf16x8 a[4], b[4];
#pragma unroll
    for (int mt = 0; mt < 4; mt++)
      a[mt] = __builtin_bit_cast(
          bf16x8, *(const ushortx8*)&As[cur][(wr + mt * 16 + lr) * BK + q * 8]);
#pragma unroll
    for (int nt = 0; nt < 4; nt++)
      b[nt] = __builtin_bit_cast(
          bf16x8, *(const ushortx8*)&Bs[cur][(wc + nt * 16 + lr) * BK + q * 8]);
#pragma unroll
    for (int mt = 0; mt < 4; mt++)
#pragma unroll
      for (int nt = 0; nt < 4; nt++)
        acc[mt][nt] = __builtin_amdgcn_mfma_f32_16x16x32_bf16(
            a[mt], b[nt], acc[mt][nt], 0, 0, 0);
  }
}

// GEMM1: Mb = bf16(A @ A)
__global__ __launch_bounds__(256, 2) void gemm_aa(const u16* __restrict__ Ab,
                                                  const u16* __restrict__ Abt,
                                                  u16* __restrict__ Mb) {
  floatx4 acc[4][4];
  gemm_tile(Ab, Abt, acc);
  const int t = threadIdx.x;
  const int lane = t & 63, w = t >> 6;
  const int wr = (w >> 1) * 64, wc = (w & 1) * 64;
  const int lr = lane & 15, q = lane >> 4;
  const int row0 = blockIdx.y * TILE, col0 = blockIdx.x * TILE;
#pragma unroll
  for (int mt = 0; mt < 4; mt++)
#pragma unroll
    for (int r = 0; r < 4; r++) {
      const int rr = row0 + wr + mt * 16 + q * 4 + r;
#pragma unroll
      for (int nt = 0; nt < 4; nt++) {
        const int cc = col0 + wc + nt * 16 + lr;
        Mb[(size_t)rr * N + cc] = f2bf(acc[mt][nt][r]);
      }
    }
}

// rdeg[i] = 1 / (4*rowsum(M)_i + 1)   (with reference's <=1e-10 guard)
__global__ void rowsum_k(const u16* __restrict__ Mb, float* __restrict__ rdeg) {
  const int row = blockIdx.x;
  const int t = threadIdx.x;
  const ushortx8 v = *((const ushortx8*)(Mb + (size_t)row * N) + t);
  float s = 0.f;
#pragma unroll
  for (int j = 0; j < 8; j++) s += bf2f(v[j]);
#pragma unroll
  for (int off = 32; off > 0; off >>= 1) s += __shfl_down(s, off, 64);
  __shared__ float ws[4];
  if ((t & 63) == 0) ws[t >> 6] = s;
  __syncthreads();
  if (t == 0) {
    float d = 4.f * (ws[0] + ws[1] + ws[2] + ws[3]) + 1.f;
    if (d <= 1e-10f) d = 1.f;
    rdeg[row] = 1.f / d;
  }
}

// GEMM2 + fused norm epilogue: out = (8*(M@A) + 2*A) * rdeg[row]
__global__ __launch_bounds__(256, 2) void gemm_ma(const u16* __restrict__ Mb,
                                                  const u16* __restrict__ Abt,
                                                  const float* __restrict__ A,
                                                  const float* __restrict__ rdeg,
                                                  float* __restrict__ out) {
  floatx4 acc[4][4];
  gemm_tile(Mb, Abt, acc);
  const int t = threadIdx.x;
  const int lane = t & 63, w = t >> 6;
  const int wr = (w >> 1) * 64, wc = (w & 1) * 64;
  const int lr = lane & 15, q = lane >> 4;
  const int row0 = blockIdx.y * TILE, col0 = blockIdx.x * TILE;
#pragma unroll
  for (int mt = 0; mt < 4; mt++)
#pragma unroll
    for (int r = 0; r < 4; r++) {
      const int rr = row0 + wr + mt * 16 + q * 4 + r;
      const float rd = rdeg[rr];
#pragma unroll
      for (int nt = 0; nt < 4; nt++) {
        const int cc = col0 + wc + nt * 16 + lr;
        out[(size_t)rr * N + cc] =
            (8.f * acc[mt][nt][r] + 2.f * A[(size_t)rr * N + cc]) * rd;
      }
    }
}

extern "C" void kernel_launch(void* const* d_in, const int* in_sizes, int n_in,
                              void* d_out, int out_size, void* d_ws, size_t ws_size,
                              hipStream_t stream) {
  const float* A = (const float*)d_in[0];
  // GTConv weights (d_in[1..3]) are irrelevant: softmax over a singleton axis
  // is identically 1, so each conv output is exactly 2*A.
  float* out = (float*)d_out;
  char* ws = (char*)d_ws;
  u16* Ab = (u16*)ws;                          // 8 MB bf16 A row-major
  u16* Abt = (u16*)(ws + NN * 2);              // 8 MB bf16 A transposed
  u16* Mb = (u16*)(ws + NN * 4);               // 8 MB bf16 M = A@A
  float* rdeg = (float*)(ws + NN * 6);         // 8 KB reciprocal degrees

  cast_tr<<<dim3(N / 32, N / 32), dim3(32, 8), 0, stream>>>(A, Ab, Abt);
  gemm_aa<<<dim3(N / TILE, N / TILE), 256, 0, stream>>>(Ab, Abt, Mb);
  rowsum_k<<<N, 256, 0, stream>>>(Mb, rdeg);
  gemm_ma<<<dim3(N / TILE, N / TILE), 256, 0, stream>>>(Mb, Abt, A, rdeg, out);
}

// Round 4
// 138.717 us; speedup vs baseline: 1.3313x; 1.1839x over previous
//
#include <hip/hip_runtime.h>
#include <stdint.h>

#define N 2048
#define TILE 128
#define BK 32
#define KI (N / BK)      // 64 K-iterations
#define LDSW 40          // padded LDS row stride in u16 (80 B) — breaks conflicts
#define NN ((size_t)N * (size_t)N)

typedef unsigned short u16;
typedef __bf16 bf16x8 __attribute__((ext_vector_type(8)));
typedef unsigned short ushortx8 __attribute__((ext_vector_type(8)));
typedef float floatx4 __attribute__((ext_vector_type(4)));

static __device__ __forceinline__ u16 f2bf(float f) {
  unsigned int u = __builtin_bit_cast(unsigned int, f);
  return (u16)((u + 0x7fffu + ((u >> 16) & 1u)) >> 16);  // RNE, finite inputs
}
static __device__ __forceinline__ float bf2f(u16 h) {
  unsigned int u = ((unsigned int)h) << 16;
  return __builtin_bit_cast(float, u);
}

// ---------------------------------------------------------------------------
// cast + transpose: Ab[r][c] = bf16(A[r][c]); Abt[c][r] = bf16(A[r][c])
// ---------------------------------------------------------------------------
__global__ void cast_tr(const float* __restrict__ A, u16* __restrict__ Ab,
                        u16* __restrict__ Abt) {
  __shared__ float tile[32][33];
  const int tx = threadIdx.x, ty = threadIdx.y;
  const int c = blockIdx.x * 32 + tx;
#pragma unroll
  for (int i = 0; i < 4; i++) {
    const int r = blockIdx.y * 32 + ty + i * 8;
    const float v = A[r * N + c];
    Ab[r * N + c] = f2bf(v);
    tile[ty + i * 8][tx] = v;
  }
  __syncthreads();
  const int r2 = blockIdx.y * 32 + tx;
#pragma unroll
  for (int i = 0; i < 4; i++) {
    const int c2 = blockIdx.x * 32 + ty + i * 8;
    Abt[c2 * N + r2] = f2bf(tile[tx][ty + i * 8]);
  }
}

// ---------------------------------------------------------------------------
// Register-staged pipelined GEMM: C = L[128 x N] * R[N x 128] (Rt in [n][k]).
// 512 threads = 8 waves (2/SIMD). Prefetch distance 3 in VGPRs via plain
// global_load_dwordx4 (compiler emits precise per-wave vmcnt before the
// dependent ds_write — no LDS-DMA alias drain). Double-buffered LDS.
// Wave w computes a 64x32 subtile: wr=(w>>2)*64, wc=(w&3)*32 -> 4x2 MFMAs.
// ---------------------------------------------------------------------------
__device__ __forceinline__ void gemm_core(const u16* __restrict__ L,
                                          const u16* __restrict__ Rt,
                                          floatx4 acc[4][2]) {
  __shared__ __align__(16) u16 As[2][TILE * LDSW];
  __shared__ __align__(16) u16 Bs[2][TILE * LDSW];

  const int t = threadIdx.x;             // 0..511
  const int row0 = blockIdx.y * TILE;
  const int col0 = blockIdx.x * TILE;

  // staging map: thread t covers row t>>2 (0..127), 16B chunk t&3 of each tile
  const int srow = t >> 2;
  const int sc = (t & 3) * 8;            // u16 offset
  const u16* gA = L + (size_t)(row0 + srow) * N + sc;
  const u16* gB = Rt + (size_t)(col0 + srow) * N + sc;
  const int woff = srow * LDSW + sc;     // LDS write offset (u16)

  const int lane = t & 63;
  const int w = t >> 6;                  // 0..7
  const int wr = (w >> 2) * 64;
  const int wc = (w & 3) * 32;
  const int lr = lane & 15;
  const int q = lane >> 4;
  const int aoff = (wr + lr) * LDSW + q * 8;
  const int boff = (wc + lr) * LDSW + q * 8;

#pragma unroll
  for (int i = 0; i < 4; i++)
#pragma unroll
    for (int j = 0; j < 2; j++) acc[i][j] = (floatx4){0.f, 0.f, 0.f, 0.f};

  ushortx8 rA[4], rB[4];
  // prologue: tiles 0..2 into registers (6 dwordx4 loads in flight per thread)
#pragma unroll
  for (int s = 0; s < 3; s++) {
    rA[s] = *(const ushortx8*)(gA + s * BK);
    rB[s] = *(const ushortx8*)(gB + s * BK);
  }
  // publish tile 0 (compiler waits only on rA[0]/rB[0]'s loads)
  *(ushortx8*)(&As[0][woff]) = rA[0];
  *(ushortx8*)(&Bs[0][woff]) = rB[0];
  __syncthreads();

#define GSTEP(i, s, cur, nxt)                                                \
  {                                                                          \
    if ((i) + 3 < KI) {                                                      \
      rA[((s) + 3) & 3] = *(const ushortx8*)(gA + ((i) + 3) * BK);           \
      rB[((s) + 3) & 3] = *(const ushortx8*)(gB + ((i) + 3) * BK);           \
    }                                                                        \
    bf16x8 af[4], bfr[2];                                                    \
    _Pragma("unroll") for (int mt = 0; mt < 4; mt++) af[mt] =                \
        __builtin_bit_cast(bf16x8,                                           \
                           *(const ushortx8*)&As[cur][aoff + mt * 16 * LDSW]); \
    _Pragma("unroll") for (int nt = 0; nt < 2; nt++) bfr[nt] =               \
        __builtin_bit_cast(bf16x8,                                           \
                           *(const ushortx8*)&Bs[cur][boff + nt * 16 * LDSW]); \
    _Pragma("unroll") for (int mt = 0; mt < 4; mt++)                         \
        _Pragma("unroll") for (int nt = 0; nt < 2; nt++) acc[mt][nt] =       \
            __builtin_amdgcn_mfma_f32_16x16x32_bf16(af[mt], bfr[nt],         \
                                                    acc[mt][nt], 0, 0, 0);   \
    __syncthreads(); /* all waves done reading buf[nxt] (last read: i-1) */  \
    if ((i) + 1 < KI) {                                                      \
      *(ushortx8*)(&As[nxt][woff]) = rA[((s) + 1) & 3];                      \
      *(ushortx8*)(&Bs[nxt][woff]) = rB[((s) + 1) & 3];                      \
    }                                                                        \
    __syncthreads(); /* publish buf[nxt] for step i+1 */                     \
  }

  for (int io = 0; io < KI; io += 4) {
    GSTEP(io + 0, 0, 0, 1)
    GSTEP(io + 1, 1, 1, 0)
    GSTEP(io + 2, 2, 0, 1)
    GSTEP(io + 3, 3, 1, 0)
  }
#undef GSTEP
}

// GEMM1: Mb = bf16(A @ A)
__global__ __launch_bounds__(512, 2) void gemm_aa(const u16* __restrict__ Ab,
                                                  const u16* __restrict__ Abt,
                                                  u16* __restrict__ Mb) {
  floatx4 acc[4][2];
  gemm_core(Ab, Abt, acc);
  const int t = threadIdx.x;
  const int lane = t & 63, w = t >> 6;
  const int wr = (w >> 2) * 64, wc = (w & 3) * 32;
  const int lr = lane & 15, q = lane >> 4;
  const int row0 = blockIdx.y * TILE, col0 = blockIdx.x * TILE;
#pragma unroll
  for (int mt = 0; mt < 4; mt++)
#pragma unroll
    for (int r = 0; r < 4; r++) {
      const int rr = row0 + wr + mt * 16 + q * 4 + r;
#pragma unroll
      for (int nt = 0; nt < 2; nt++) {
        const int cc = col0 + wc + nt * 16 + lr;
        Mb[(size_t)rr * N + cc] = f2bf(acc[mt][nt][r]);
      }
    }
}

// rdeg[i] = 1 / (4*rowsum(M)_i + 1)   (with reference's <=1e-10 guard)
__global__ void rowsum_k(const u16* __restrict__ Mb, float* __restrict__ rdeg) {
  const int row = blockIdx.x;
  const int t = threadIdx.x;
  const ushortx8 v = *((const ushortx8*)(Mb + (size_t)row * N) + t);
  float s = 0.f;
#pragma unroll
  for (int j = 0; j < 8; j++) s += bf2f(v[j]);
#pragma unroll
  for (int off = 32; off > 0; off >>= 1) s += __shfl_down(s, off, 64);
  __shared__ float ws[4];
  if ((t & 63) == 0) ws[t >> 6] = s;
  __syncthreads();
  if (t == 0) {
    float d = 4.f * (ws[0] + ws[1] + ws[2] + ws[3]) + 1.f;
    if (d <= 1e-10f) d = 1.f;
    rdeg[row] = 1.f / d;
  }
}

// GEMM2 + fused norm epilogue: out = (8*(M@A) + 2*A) * rdeg[row]
__global__ __launch_bounds__(512, 2) void gemm_ma(const u16* __restrict__ Mb,
                                                  const u16* __restrict__ Abt,
                                                  const float* __restrict__ A,
                                                  const float* __restrict__ rdeg,
                                                  float* __restrict__ out) {
  floatx4 acc[4][2];
  gemm_core(Mb, Abt, acc);
  const int t = threadIdx.x;
  const int lane = t & 63, w = t >> 6;
  const int wr = (w >> 2) * 64, wc = (w & 3) * 32;
  const int lr = lane & 15, q = lane >> 4;
  const int row0 = blockIdx.y * TILE, col0 = blockIdx.x * TILE;
#pragma unroll
  for (int mt = 0; mt < 4; mt++)
#pragma unroll
    for (int r = 0; r < 4; r++) {
      const int rr = row0 + wr + mt * 16 + q * 4 + r;
      const float rd = rdeg[rr];
#pragma unroll
      for (int nt = 0; nt < 2; nt++) {
        const int cc = col0 + wc + nt * 16 + lr;
        out[(size_t)rr * N + cc] =
            (8.f * acc[mt][nt][r] + 2.f * A[(size_t)rr * N + cc]) * rd;
      }
    }
}

extern "C" void kernel_launch(void* const* d_in, const int* in_sizes, int n_in,
                              void* d_out, int out_size, void* d_ws, size_t ws_size,
                              hipStream_t stream) {
  const float* A = (const float*)d_in[0];
  // GTConv weights (d_in[1..3]) are irrelevant: softmax over a singleton axis
  // is identically 1, so each conv output is exactly 2*A.
  float* out = (float*)d_out;
  char* ws = (char*)d_ws;
  u16* Ab = (u16*)ws;                          // 8 MB bf16 A row-major
  u16* Abt = (u16*)(ws + NN * 2);              // 8 MB bf16 A transposed
  u16* Mb = (u16*)(ws + NN * 4);               // 8 MB bf16 M = A@A
  float* rdeg = (float*)(ws + NN * 6);         // 8 KB reciprocal degrees

  cast_tr<<<dim3(N / 32, N / 32), dim3(32, 8), 0, stream>>>(A, Ab, Abt);
  gemm_aa<<<dim3(N / TILE, N / TILE), 512, 0, stream>>>(Ab, Abt, Mb);
  rowsum_k<<<N, 256, 0, stream>>>(Mb, rdeg);
  gemm_ma<<<dim3(N / TILE, N / TILE), 512, 0, stream>>>(Mb, Abt, A, rdeg, out);
}